// Round 3
// baseline (986.466 us; speedup 1.0000x reference)
//
#include <hip/hip_runtime.h>
#include <hip/hip_bf16.h>

typedef __hip_bfloat16 bf16;
typedef unsigned short u16;
typedef unsigned int uint32;

#define BATCH   128
#define LSIG    128
#define PL      16
#define ST      4
#define WIN     4
#define NPATCH  29
#define NG      (BATCH * NPATCH)   // 3712
#define NNODE   (NG * PL)          // 59392
#define HID     256
#define NCLS    8

// f32 workspace param layout (element offsets)
#define IQ_OFF    0
#define W0A_OFF   32768
#define W0R_OFF   33280
#define B0_OFF    33792
#define WAT_OFF   34048
#define WRT_OFF   230656
#define BLIN_OFF  427264
#define LNS_OFF   428032
#define LNB_OFF   429056
#define W1T_OFF   430080
#define CB1_OFF   495616
#define CLNS_OFF  495872
#define CLNB_OFF  496128
#define CW2_OFF   496384
#define CB2_OFF   498432
#define CVT_TOTAL 498440

#define A_BYTE_OFF   2101248          // bf16 activation buffer in ws (after flag+params)
#define B_BYTE_OFF   1959936          // bf16 scratch window inside d_out (safe both dtypes)
#define LOGIT_EOFF   0                // d_out element offsets
#define GF_EOFF      (NG * NCLS)                  // 29696
#define EMB_EOFF     (NG * NCLS + NG * HID)       // 979968

__device__ __forceinline__ float b2f(bf16 x) { return __bfloat162float(x); }
__device__ __forceinline__ float ldmix(const void* p, int i, int fl) {
  return fl ? ((const float*)p)[i] : __bfloat162float(((const bf16*)p)[i]);
}

// -------- dtype detector: even 16-bit slots of iq discriminate bf16 vs f32 --------
__global__ __launch_bounds__(256) void detect_kernel(const u16* __restrict__ iq, int* flag) {
  __shared__ int sbig, snz;
  int t = threadIdx.x;
  if (t == 0) { sbig = 0; snz = 0; }
  __syncthreads();
  int big = 0, nz = 0;
  for (int e = t; e < 16384; e += 256) {
    u16 u = iq[2 * e];
    int ex = (u >> 7) & 0xFF;
    if (ex >= 0xC0) big++;          // |x| >= 2^65 as bf16 -> not real data
    if (u != 0) nz++;
  }
  atomicAdd(&sbig, big); atomicAdd(&snz, nz);
  __syncthreads();
  if (t == 0) *flag = (sbig > 4 || snz < 100) ? 1 : 0;   // 1 = f32 inputs
}

// -------- normalize all float inputs into f32 ws (weights transposed) --------
__global__ __launch_bounds__(256) void convert_all(
    const int* __restrict__ flag,
    const void* iq, const void* w0a, const void* w0r, const void* b0,
    const void* wag, const void* wro, const void* blin,
    const void* lns, const void* lnb,
    const void* cw1, const void* cb1, const void* clns, const void* clnb,
    const void* cw2, const void* cb2,
    float* __restrict__ P) {
  int idx = blockIdx.x * 256 + threadIdx.x;
  if (idx >= CVT_TOTAL) return;
  int fl = *flag;
  float v;
  if (idx < W0A_OFF)        v = ldmix(iq,  idx - IQ_OFF, fl);
  else if (idx < W0R_OFF)   v = ldmix(w0a, idx - W0A_OFF, fl);
  else if (idx < B0_OFF)    v = ldmix(w0r, idx - W0R_OFF, fl);
  else if (idx < WAT_OFF)   v = ldmix(b0,  idx - B0_OFF, fl);
  else if (idx < WRT_OFF) { int t2 = idx - WAT_OFF; int l = t2 >> 16, r = t2 & 65535;
    v = ldmix(wag, l * 65536 + (r & 255) * 256 + (r >> 8), fl); }
  else if (idx < BLIN_OFF) { int t2 = idx - WRT_OFF; int l = t2 >> 16, r = t2 & 65535;
    v = ldmix(wro, l * 65536 + (r & 255) * 256 + (r >> 8), fl); }
  else if (idx < LNS_OFF)   v = ldmix(blin, idx - BLIN_OFF, fl);
  else if (idx < LNB_OFF)   v = ldmix(lns, idx - LNS_OFF, fl);
  else if (idx < W1T_OFF)   v = ldmix(lnb, idx - LNB_OFF, fl);
  else if (idx < CB1_OFF) { int t2 = idx - W1T_OFF;
    v = ldmix(cw1, (t2 & 255) * 256 + (t2 >> 8), fl); }
  else if (idx < CLNS_OFF)  v = ldmix(cb1, idx - CB1_OFF, fl);
  else if (idx < CLNB_OFF)  v = ldmix(clns, idx - CLNS_OFF, fl);
  else if (idx < CW2_OFF)   v = ldmix(clnb, idx - CLNB_OFF, fl);
  else if (idx < CB2_OFF)   v = ldmix(cw2, idx - CW2_OFF, fl);
  else                      v = ldmix(cb2, idx - CB2_OFF, fl);
  P[idx] = v;
}

// -------- layer 0: patch extract + SAGE(2->256) + LN + ReLU --------
__global__ __launch_bounds__(256) void layer0_kernel(
    const float* __restrict__ P, bf16* __restrict__ hout) {
  int g = blockIdx.x, f = threadIdx.x;
  int b = g / NPATCH, p = g % NPATCH;
  __shared__ float x_s[PL][2];
  __shared__ float xp_s[2];
  __shared__ float agg_s[PL][2];
  __shared__ float o_s[PL][HID];
  __shared__ float mv_s[PL][2];
  if (f < 32) { int j = f & 15, c = f >> 4;
    x_s[j][c] = P[IQ_OFF + (b * 2 + c) * LSIG + p * ST + j]; }
  if (f < 2) xp_s[f] = (p > 0) ? P[IQ_OFF + (b * 2 + f) * LSIG + (p - 1) * ST + PL - 1] : 0.f;
  __syncthreads();
  if (f < 32) { int j = f & 15, c = f >> 4;
    float s = 0.f;
    int lo = j - WIN < 0 ? 0 : j - WIN, hi = j + WIN > 15 ? 15 : j + WIN;
    for (int i = lo; i <= hi; ++i) if (i != j) s += x_s[i][c];
    int deg = (j < WIN ? j : WIN) + ((15 - j) < WIN ? (15 - j) : WIN);
    if (j == 0 && p > 0) { s += xp_s[c]; deg += 1; }
    agg_s[j][c] = s / (float)deg;
  }
  __syncthreads();
  float wa0 = P[W0A_OFF + f * 2], wa1 = P[W0A_OFF + f * 2 + 1];
  float wr0 = P[W0R_OFF + f * 2], wr1 = P[W0R_OFF + f * 2 + 1];
  float bb = P[B0_OFF + f];
#pragma unroll
  for (int j = 0; j < PL; ++j)
    o_s[j][f] = agg_s[j][0] * wa0 + agg_s[j][1] * wa1 + x_s[j][0] * wr0 + x_s[j][1] * wr1 + bb;
  __syncthreads();
  { int j = f >> 4, q = f & 15;
    float s = 0.f, s2 = 0.f;
#pragma unroll
    for (int i = 0; i < 16; ++i) { float v = o_s[j][q + 16 * i]; s += v; s2 += v * v; }
#pragma unroll
    for (int m = 8; m >= 1; m >>= 1) { s += __shfl_xor(s, m); s2 += __shfl_xor(s2, m); }
    if (q == 0) { float mean = s * (1.f / HID);
      float var = s2 * (1.f / HID) - mean * mean;
      mv_s[j][0] = mean; mv_s[j][1] = rsqrtf(var + 1e-5f); }
  }
  __syncthreads();
  float gl = P[LNS_OFF + f], bl = P[LNB_OFF + f];
#pragma unroll
  for (int j = 0; j < PL; ++j) {
    float v = (o_s[j][f] - mv_s[j][0]) * mv_s[j][1] * gl + bl;
    v = v > 0.f ? v : 0.f;
    hout[(size_t)(g * PL + j) * HID + f] = __float2bfloat16(v);
  }
}

// -------- SAGE layer (256->256) + LN + ReLU + residual --------
__global__ __launch_bounds__(256) void sage_layer(
    const bf16* __restrict__ hin,
    const float* __restrict__ WaT, const float* __restrict__ WrT,
    const float* __restrict__ bvec,
    const float* __restrict__ lng, const float* __restrict__ lnb,
    bf16* __restrict__ hout) {
  int g = blockIdx.x, f = threadIdx.x;
  int p = g % NPATCH;
  __shared__ float h_s[PL + 1][HID];   // row 0 = prev patch's node 15
  __shared__ float o_s[PL][HID];       // agg, then outputs
  __shared__ float mv_s[PL][2];
  const bf16* hb = hin + (size_t)g * PL * HID;
#pragma unroll
  for (int r = 0; r < PL; ++r) h_s[r + 1][f] = b2f(hb[r * HID + f]);
  h_s[0][f] = (p > 0) ? b2f(hb[f - HID]) : 0.f;
  __syncthreads();
#pragma unroll
  for (int j = 0; j < PL; ++j) {
    float s = 0.f;
    int lo = j - WIN < 0 ? 0 : j - WIN, hi = j + WIN > 15 ? 15 : j + WIN;
    for (int i = lo; i <= hi; ++i) if (i != j) s += h_s[1 + i][f];
    int deg = (j < WIN ? j : WIN) + ((15 - j) < WIN ? (15 - j) : WIN);
    if (j == 0 && p > 0) { s += h_s[0][f]; deg += 1; }
    o_s[j][f] = s * (1.f / (float)deg);
  }
  __syncthreads();
  float acc[PL];
  float bb = bvec[f];
#pragma unroll
  for (int j = 0; j < PL; ++j) acc[j] = bb;
  for (int k = 0; k < HID; k += 4) {
    float wa[4], wr[4];
#pragma unroll
    for (int u = 0; u < 4; ++u) { wa[u] = WaT[(k + u) * HID + f]; wr[u] = WrT[(k + u) * HID + f]; }
#pragma unroll
    for (int j = 0; j < PL; ++j) {
      const float4 a  = *(const float4*)(&o_s[j][k]);
      const float4 hh = *(const float4*)(&h_s[j + 1][k]);
      acc[j] = fmaf(a.x,  wa[0], acc[j]); acc[j] = fmaf(a.y,  wa[1], acc[j]);
      acc[j] = fmaf(a.z,  wa[2], acc[j]); acc[j] = fmaf(a.w,  wa[3], acc[j]);
      acc[j] = fmaf(hh.x, wr[0], acc[j]); acc[j] = fmaf(hh.y, wr[1], acc[j]);
      acc[j] = fmaf(hh.z, wr[2], acc[j]); acc[j] = fmaf(hh.w, wr[3], acc[j]);
    }
  }
  __syncthreads();
#pragma unroll
  for (int j = 0; j < PL; ++j) o_s[j][f] = acc[j];
  __syncthreads();
  { int j = f >> 4, q = f & 15;
    float s = 0.f, s2 = 0.f;
#pragma unroll
    for (int i = 0; i < 16; ++i) { float v = o_s[j][q + 16 * i]; s += v; s2 += v * v; }
#pragma unroll
    for (int m = 8; m >= 1; m >>= 1) { s += __shfl_xor(s, m); s2 += __shfl_xor(s2, m); }
    if (q == 0) { float mean = s * (1.f / HID);
      float var = s2 * (1.f / HID) - mean * mean;
      mv_s[j][0] = mean; mv_s[j][1] = rsqrtf(var + 1e-5f); }
  }
  __syncthreads();
  float gl = lng[f], bl = lnb[f];
#pragma unroll
  for (int j = 0; j < PL; ++j) {
    float v = (o_s[j][f] - mv_s[j][0]) * mv_s[j][1] * gl + bl;
    v = v > 0.f ? v : 0.f;
    float res = h_s[1 + j][f] + v;
    hout[(size_t)(g * PL + j) * HID + f] = __float2bfloat16(res);
  }
}

// -------- head: mean-pool + MLP + LN + ReLU + logits (+gf) --------
__global__ __launch_bounds__(256) void head_kernel(
    const bf16* __restrict__ emb, const float* __restrict__ P,
    void* __restrict__ dout, const int* __restrict__ flag) {
  int g = blockIdx.x, f = threadIdx.x;
  int fl = *flag;
  __shared__ float gf_s[HID];
  __shared__ float z_s[HID];
  __shared__ float ps[4], ps2[4];
  __shared__ float mr[2];
  const bf16* eb = emb + (size_t)g * PL * HID;
  float s = 0.f;
#pragma unroll
  for (int r = 0; r < PL; ++r) s += b2f(eb[r * HID + f]);
  s *= (1.f / PL);
  gf_s[f] = s;
  { size_t ei = (size_t)GF_EOFF + (size_t)g * HID + f;
    if (fl) ((float*)dout)[ei] = s; else ((bf16*)dout)[ei] = __float2bfloat16(s); }
  __syncthreads();
  float acc = P[CB1_OFF + f];
  for (int k = 0; k < HID; k += 4) {
    const float4 gv = *(const float4*)(&gf_s[k]);
    acc = fmaf(gv.x, P[W1T_OFF + (k + 0) * HID + f], acc);
    acc = fmaf(gv.y, P[W1T_OFF + (k + 1) * HID + f], acc);
    acc = fmaf(gv.z, P[W1T_OFF + (k + 2) * HID + f], acc);
    acc = fmaf(gv.w, P[W1T_OFF + (k + 3) * HID + f], acc);
  }
  float s1 = acc, s2 = acc * acc;
#pragma unroll
  for (int m = 32; m >= 1; m >>= 1) { s1 += __shfl_xor(s1, m); s2 += __shfl_xor(s2, m); }
  int wid = f >> 6, lane = f & 63;
  if (lane == 0) { ps[wid] = s1; ps2[wid] = s2; }
  __syncthreads();
  if (f == 0) {
    float S = ps[0] + ps[1] + ps[2] + ps[3];
    float S2 = ps2[0] + ps2[1] + ps2[2] + ps2[3];
    float mean = S * (1.f / HID);
    mr[0] = mean; mr[1] = rsqrtf(S2 * (1.f / HID) - mean * mean + 1e-5f);
  }
  __syncthreads();
  float z = (acc - mr[0]) * mr[1] * P[CLNS_OFF + f] + P[CLNB_OFF + f];
  z = z > 0.f ? z : 0.f;
  z_s[f] = z;
  __syncthreads();
  if (f < NCLS) {
    float a = P[CB2_OFF + f];
    for (int k = 0; k < HID; ++k) a = fmaf(z_s[k], P[CW2_OFF + f * HID + k], a);
    size_t ei = (size_t)LOGIT_EOFF + (size_t)g * NCLS + f;
    if (fl) ((float*)dout)[ei] = a; else ((bf16*)dout)[ei] = __float2bfloat16(a);
  }
}

// -------- emit node_emb in output dtype --------
__global__ __launch_bounds__(256) void emit_emb(
    const bf16* __restrict__ A, void* __restrict__ dout, const int* __restrict__ flag) {
  int fl = *flag;
  size_t n = (size_t)NNODE * HID;
  for (size_t i = blockIdx.x * 256ull + threadIdx.x; i < n; i += 2048ull * 256ull) {
    bf16 v = A[i];
    size_t ei = (size_t)EMB_EOFF + i;
    if (fl) ((float*)dout)[ei] = b2f(v); else ((bf16*)dout)[ei] = v;
  }
}

extern "C" void kernel_launch(void* const* d_in, const int* in_sizes, int n_in,
                              void* d_out, int out_size, void* d_ws, size_t ws_size,
                              hipStream_t stream) {
  char* ws = (char*)d_ws;
  int*   flag = (int*)ws;
  float* P    = (float*)(ws + 4096);
  bf16*  A    = (bf16*)(ws + A_BYTE_OFF);                 // 30.4 MB
  bf16*  B    = (bf16*)((char*)d_out + B_BYTE_OFF);       // scratch window in d_out

  detect_kernel<<<1, 256, 0, stream>>>((const u16*)d_in[0], flag);
  convert_all<<<(CVT_TOTAL + 255) / 256, 256, 0, stream>>>(
      flag, d_in[0], d_in[3], d_in[4], d_in[5], d_in[6], d_in[7], d_in[8],
      d_in[9], d_in[10], d_in[11], d_in[12], d_in[13], d_in[14], d_in[15], d_in[16], P);

  layer0_kernel<<<NG, 256, 0, stream>>>(P, B);
  sage_layer<<<NG, 256, 0, stream>>>(B, P + WAT_OFF, P + WRT_OFF,
      P + BLIN_OFF, P + LNS_OFF + HID, P + LNB_OFF + HID, A);
  sage_layer<<<NG, 256, 0, stream>>>(A, P + WAT_OFF + 65536, P + WRT_OFF + 65536,
      P + BLIN_OFF + HID, P + LNS_OFF + 2 * HID, P + LNB_OFF + 2 * HID, B);
  sage_layer<<<NG, 256, 0, stream>>>(B, P + WAT_OFF + 2 * 65536, P + WRT_OFF + 2 * 65536,
      P + BLIN_OFF + 2 * HID, P + LNS_OFF + 3 * HID, P + LNB_OFF + 3 * HID, A);
  head_kernel<<<NG, 256, 0, stream>>>(A, P, d_out, flag);
  emit_emb<<<2048, 256, 0, stream>>>(A, d_out, flag);
}

// Round 5
// 310.329 us; speedup vs baseline: 3.1788x; 3.1788x over previous
//
#include <hip/hip_runtime.h>
#include <hip/hip_bf16.h>

typedef __hip_bfloat16 bf16;
typedef unsigned short u16;
typedef unsigned int uint32;
typedef __attribute__((ext_vector_type(8))) short bf16x8;
typedef __attribute__((ext_vector_type(4))) float f32x4;

#define BATCH   128
#define LSIG    128
#define PL      16
#define ST      4
#define WIN     4
#define NPATCH  29
#define NG      (BATCH * NPATCH)   // 3712
#define NNODE   (NG * PL)          // 59392
#define HID     256
#define NCLS    8

// f32 param workspace layout (element offsets)
#define IQ_OFF    0
#define W0A_OFF   32768
#define W0R_OFF   33280
#define B0_OFF    33792
#define BLIN_OFF  34048
#define LNS_OFF   34816
#define LNB_OFF   35840
#define W1T_OFF   36864
#define CB1_OFF   102400
#define CLNS_OFF  102656
#define CLNB_OFF  102912
#define CW2_OFF   103168
#define CB2_OFF   105216
#define CVT_TOTAL 105224

#define P_BYTE_OFF   4096
#define WB_BYTE_OFF  425984           // bf16 sage weights: 3 layers x (Wa|Wr) x 65536
#define A_BYTE_OFF   1216512          // bf16 activation buffer (30.4 MB)
#define B_BYTE_OFF   1959936          // bf16 scratch window inside d_out
#define GF_EOFF      (NG * NCLS)
#define EMB_EOFF     (NG * NCLS + NG * HID)

__device__ __forceinline__ float b2f(bf16 x) { return __bfloat162float(x); }
__device__ __forceinline__ float ldmix(const void* p, int i, int fl) {
  return fl ? ((const float*)p)[i] : __bfloat162float(((const bf16*)p)[i]);
}

// -------- dtype detector --------
__global__ __launch_bounds__(256) void detect_kernel(const u16* __restrict__ iq, int* flag) {
  __shared__ int sbig, snz;
  int t = threadIdx.x;
  if (t == 0) { sbig = 0; snz = 0; }
  __syncthreads();
  int big = 0, nz = 0;
  for (int e = t; e < 16384; e += 256) {
    u16 u = iq[2 * e];
    int ex = (u >> 7) & 0xFF;
    if (ex >= 0xC0) big++;
    if (u != 0) nz++;
  }
  atomicAdd(&sbig, big); atomicAdd(&snz, nz);
  __syncthreads();
  if (t == 0) *flag = (sbig > 4 || snz < 100) ? 1 : 0;   // 1 = f32 inputs
}

// -------- params -> f32 P --------
__global__ __launch_bounds__(256) void convert_params(
    const int* __restrict__ flag,
    const void* iq, const void* w0a, const void* w0r, const void* b0,
    const void* blin, const void* lns, const void* lnb,
    const void* cw1, const void* cb1, const void* clns, const void* clnb,
    const void* cw2, const void* cb2,
    float* __restrict__ P) {
  int idx = blockIdx.x * 256 + threadIdx.x;
  if (idx >= CVT_TOTAL) return;
  int fl = *flag;
  float v;
  if (idx < W0A_OFF)        v = ldmix(iq,  idx, fl);
  else if (idx < W0R_OFF)   v = ldmix(w0a, idx - W0A_OFF, fl);
  else if (idx < B0_OFF)    v = ldmix(w0r, idx - W0R_OFF, fl);
  else if (idx < BLIN_OFF)  v = ldmix(b0,  idx - B0_OFF, fl);
  else if (idx < LNS_OFF)   v = ldmix(blin, idx - BLIN_OFF, fl);
  else if (idx < LNB_OFF)   v = ldmix(lns, idx - LNS_OFF, fl);
  else if (idx < W1T_OFF)   v = ldmix(lnb, idx - LNB_OFF, fl);
  else if (idx < CB1_OFF) { int t2 = idx - W1T_OFF;
    v = ldmix(cw1, (t2 & 255) * 256 + (t2 >> 8), fl); }
  else if (idx < CLNS_OFF)  v = ldmix(cb1, idx - CB1_OFF, fl);
  else if (idx < CLNB_OFF)  v = ldmix(clns, idx - CLNS_OFF, fl);
  else if (idx < CW2_OFF)   v = ldmix(clnb, idx - CLNB_OFF, fl);
  else if (idx < CB2_OFF)   v = ldmix(cw2, idx - CW2_OFF, fl);
  else                      v = ldmix(cb2, idx - CB2_OFF, fl);
  P[idx] = v;
}

// -------- sage weights -> bf16 WB ([f][k] layout kept) --------
__global__ __launch_bounds__(256) void convert_wb(
    const int* __restrict__ flag, const void* wag, const void* wro, bf16* __restrict__ WB) {
  int idx = blockIdx.x * 256 + threadIdx.x;   // < 393216
  int fl = *flag;
  int l = idx >> 17, m = (idx >> 16) & 1, r = idx & 65535;
  const void* src = m ? wro : wag;
  WB[idx] = __float2bfloat16(ldmix(src, l * 65536 + r, fl));
}

// -------- layer 0: patch extract + SAGE(2->256) + LN + ReLU --------
__global__ __launch_bounds__(256) void layer0_kernel(
    const float* __restrict__ P, bf16* __restrict__ hout) {
  int g = blockIdx.x, f = threadIdx.x;
  int b = g / NPATCH, p = g % NPATCH;
  __shared__ float x_s[PL][2];
  __shared__ float xp_s[2];
  __shared__ float agg_s[PL][2];
  __shared__ float o_s[PL][HID];
  __shared__ float mv_s[PL][2];
  if (f < 32) { int j = f & 15, c = f >> 4;
    x_s[j][c] = P[IQ_OFF + (b * 2 + c) * LSIG + p * ST + j]; }
  if (f < 2) xp_s[f] = (p > 0) ? P[IQ_OFF + (b * 2 + f) * LSIG + (p - 1) * ST + PL - 1] : 0.f;
  __syncthreads();
  if (f < 32) { int j = f & 15, c = f >> 4;
    float s = 0.f;
    int lo = j - WIN < 0 ? 0 : j - WIN, hi = j + WIN > 15 ? 15 : j + WIN;
    for (int i = lo; i <= hi; ++i) if (i != j) s += x_s[i][c];
    int deg = (j < WIN ? j : WIN) + ((15 - j) < WIN ? (15 - j) : WIN);
    if (j == 0 && p > 0) { s += xp_s[c]; deg += 1; }
    agg_s[j][c] = s / (float)deg;
  }
  __syncthreads();
  float wa0 = P[W0A_OFF + f * 2], wa1 = P[W0A_OFF + f * 2 + 1];
  float wr0 = P[W0R_OFF + f * 2], wr1 = P[W0R_OFF + f * 2 + 1];
  float bb = P[B0_OFF + f];
#pragma unroll
  for (int j = 0; j < PL; ++j)
    o_s[j][f] = agg_s[j][0] * wa0 + agg_s[j][1] * wa1 + x_s[j][0] * wr0 + x_s[j][1] * wr1 + bb;
  __syncthreads();
  { int j = f >> 4, q = f & 15;
    float s = 0.f, s2 = 0.f;
#pragma unroll
    for (int i = 0; i < 16; ++i) { float v = o_s[j][q + 16 * i]; s += v; s2 += v * v; }
#pragma unroll
    for (int m = 8; m >= 1; m >>= 1) { s += __shfl_xor(s, m); s2 += __shfl_xor(s2, m); }
    if (q == 0) { float mean = s * (1.f / HID);
      float var = s2 * (1.f / HID) - mean * mean;
      mv_s[j][0] = mean; mv_s[j][1] = rsqrtf(var + 1e-5f); }
  }
  __syncthreads();
  float gl = P[LNS_OFF + f], bl = P[LNB_OFF + f];
#pragma unroll
  for (int j = 0; j < PL; ++j) {
    float v = (o_s[j][f] - mv_s[j][0]) * mv_s[j][1] * gl + bl;
    v = v > 0.f ? v : 0.f;
    hout[(size_t)(g * PL + j) * HID + f] = __float2bfloat16(v);
  }
}

// -------- SAGE layer 256->256 via MFMA + LN + ReLU + residual --------
#define BP  2
#define BM  32
#define LDH 264
__global__ __launch_bounds__(256) void sage_mfma(
    const bf16* __restrict__ hin,
    const bf16* __restrict__ Wa, const bf16* __restrict__ Wr,
    const float* __restrict__ bias,
    const float* __restrict__ lng, const float* __restrict__ lnb,
    bf16* __restrict__ hout) {
  int t = threadIdx.x;
  int g0 = blockIdx.x * BP;
  size_t nbase = (size_t)g0 * PL;
  __shared__ bf16 h_s[BM + 1][LDH];   // rows 0..31 local nodes; row 32 = prev-patch node 15
  __shared__ bf16 ag_s[BM][LDH];      // agg (bf16), later reused as o (bf16)
  __shared__ float mv_s[BM][2];

  // ---- stage h: 32 rows x 256 bf16 = 1024 x 16B units ----
  const bf16* src = hin + nbase * HID;
#pragma unroll
  for (int it = 0; it < 4; ++it) {
    int u = it * 256 + t;            // 16B unit index, 1024 total
    int row = u >> 5, uc = u & 31;
    *(uint4*)&h_s[row][uc * 8] = *(const uint4*)(src + u * 8);
  }
  if (t < 32) {
    uint4 v = make_uint4(0u, 0u, 0u, 0u);
    if ((g0 % NPATCH) != 0) v = *(const uint4*)(src - HID + t * 8);
    *(uint4*)&h_s[BM][t * 8] = v;
  }
  __syncthreads();

  // ---- agg (windowed mean, f32 -> bf16) ----
  {
    int c2 = t & 127, Pp = t >> 7;
    int hp = ((g0 + Pp) % NPATCH) != 0;
    int brow = Pp ? (Pp * PL - 1) : BM;
    float vlo[16], vhi[16];
#pragma unroll
    for (int j = 0; j < 16; ++j) {
      uint32 u = *(const uint32*)&h_s[Pp * PL + j][c2 * 2];
      vlo[j] = __uint_as_float(u << 16);
      vhi[j] = __uint_as_float(u & 0xFFFF0000u);
    }
    float blo = 0.f, bhi = 0.f;
    if (hp) { uint32 u = *(const uint32*)&h_s[brow][c2 * 2];
      blo = __uint_as_float(u << 16); bhi = __uint_as_float(u & 0xFFFF0000u); }
#pragma unroll
    for (int j = 0; j < 16; ++j) {
      const int a = (j - WIN < 0) ? 0 : j - WIN;
      const int b = (j + WIN > 15) ? 15 : j + WIN;
      float slo = 0.f, shi = 0.f;
#pragma unroll
      for (int i = 0; i < 16; ++i)
        if (i >= a && i <= b && i != j) { slo += vlo[i]; shi += vhi[i]; }
      float deg = (float)((j < WIN ? j : WIN) + (15 - j < WIN ? 15 - j : WIN));
      if (j == 0 && hp) { slo += blo; shi += bhi; deg += 1.f; }
      float inv = 1.f / deg;
      bf16 r0 = __float2bfloat16(slo * inv), r1 = __float2bfloat16(shi * inv);
      uint32 wv = ((uint32)(*(const u16*)&r1) << 16) | (uint32)(*(const u16*)&r0);
      *(uint32*)&ag_s[Pp * PL + j][c2 * 2] = wv;
    }
  }
  __syncthreads();

  // ---- MFMA GEMM: out = agg@Wa^T + h@Wr^T ----
  int w = t >> 6, l = t & 63;
  int lr = l & 15, lg = l >> 4;
  int colbase = w * 64;
  f32x4 acc[2][4];
#pragma unroll
  for (int m = 0; m < 2; ++m)
#pragma unroll
    for (int n = 0; n < 4; ++n) acc[m][n] = (f32x4){0.f, 0.f, 0.f, 0.f};
  const bf16* waB = Wa + (colbase + lr) * HID + lg * 8;
  const bf16* wrB = Wr + (colbase + lr) * HID + lg * 8;
#pragma unroll
  for (int ks = 0; ks < 8; ++ks) {
    int acol = ks * 32 + lg * 8;
    bf16x8 agf[2], hf[2];
#pragma unroll
    for (int m = 0; m < 2; ++m) {
      agf[m] = *(const bf16x8*)&ag_s[m * 16 + lr][acol];
      hf[m]  = *(const bf16x8*)&h_s[m * 16 + lr][acol];
    }
#pragma unroll
    for (int nt = 0; nt < 4; ++nt) {
      bf16x8 waf = *(const bf16x8*)(waB + nt * 16 * HID + ks * 32);
      bf16x8 wrf = *(const bf16x8*)(wrB + nt * 16 * HID + ks * 32);
#pragma unroll
      for (int m = 0; m < 2; ++m) {
        acc[m][nt] = __builtin_amdgcn_mfma_f32_16x16x32_bf16(agf[m], waf, acc[m][nt], 0, 0, 0);
        acc[m][nt] = __builtin_amdgcn_mfma_f32_16x16x32_bf16(hf[m],  wrf, acc[m][nt], 0, 0, 0);
      }
    }
  }
  // bias
#pragma unroll
  for (int nt = 0; nt < 4; ++nt) {
    float bv = bias[colbase + nt * 16 + lr];
#pragma unroll
    for (int m = 0; m < 2; ++m) {
      acc[m][nt][0] += bv; acc[m][nt][1] += bv;
      acc[m][nt][2] += bv; acc[m][nt][3] += bv;
    }
  }
  __syncthreads();                 // all waves done reading ag_s/h_s frags
  // store o (bf16) into ag_s; D layout: col=lane&15, row=(lane>>4)*4+reg  [m89]
#pragma unroll
  for (int m = 0; m < 2; ++m)
#pragma unroll
    for (int nt = 0; nt < 4; ++nt) {
      int col = colbase + nt * 16 + lr;
#pragma unroll
      for (int r = 0; r < 4; ++r) {
        int row = m * 16 + lg * 4 + r;
        ag_s[row][col] = __float2bfloat16(acc[m][nt][r]);
      }
    }
  __syncthreads();

  // ---- LN stats: 8 threads per row ----
  {
    int row = t >> 3, q = t & 7;
    float s = 0.f, s2 = 0.f;
#pragma unroll
    for (int i = 0; i < 16; ++i) {
      uint32 u = *(const uint32*)&ag_s[row][q * 32 + i * 2];
      float a = __uint_as_float(u << 16), b = __uint_as_float(u & 0xFFFF0000u);
      s += a + b; s2 += a * a + b * b;
    }
    s += __shfl_xor(s, 1); s2 += __shfl_xor(s2, 1);
    s += __shfl_xor(s, 2); s2 += __shfl_xor(s2, 2);
    s += __shfl_xor(s, 4); s2 += __shfl_xor(s2, 4);
    if (q == 0) { float mean = s * (1.f / HID);
      mv_s[row][0] = mean;
      mv_s[row][1] = rsqrtf(s2 * (1.f / HID) - mean * mean + 1e-5f); }
  }
  __syncthreads();

  // ---- LN + ReLU + residual + store ----
  {
    int c2 = t & 127, half = t >> 7;
    float g0v = lng[c2 * 2], g1v = lng[c2 * 2 + 1];
    float b0v = lnb[c2 * 2], b1v = lnb[c2 * 2 + 1];
    bf16* dst = hout + nbase * HID;
#pragma unroll
    for (int i = 0; i < 16; ++i) {
      int row = half * 16 + i;
      uint32 u = *(const uint32*)&ag_s[row][c2 * 2];
      float a = __uint_as_float(u << 16), b = __uint_as_float(u & 0xFFFF0000u);
      float mean = mv_s[row][0], rstd = mv_s[row][1];
      a = (a - mean) * rstd * g0v + b0v; a = a > 0.f ? a : 0.f;
      b = (b - mean) * rstd * g1v + b1v; b = b > 0.f ? b : 0.f;
      uint32 hu = *(const uint32*)&h_s[row][c2 * 2];
      a += __uint_as_float(hu << 16);
      b += __uint_as_float(hu & 0xFFFF0000u);
      bf16 r0 = __float2bfloat16(a), r1 = __float2bfloat16(b);
      uint32 wv = ((uint32)(*(const u16*)&r1) << 16) | (uint32)(*(const u16*)&r0);
      *(uint32*)(dst + (size_t)row * HID + c2 * 2) = wv;
    }
  }
}

// -------- head --------
__global__ __launch_bounds__(256) void head_kernel(
    const bf16* __restrict__ emb, const float* __restrict__ P,
    void* __restrict__ dout, const int* __restrict__ flag) {
  int g = blockIdx.x, f = threadIdx.x;
  int fl = *flag;
  __shared__ float gf_s[HID];
  __shared__ float z_s[HID];
  __shared__ float ps[4], ps2[4];
  __shared__ float mr[2];
  const bf16* eb = emb + (size_t)g * PL * HID;
  float s = 0.f;
#pragma unroll
  for (int r = 0; r < PL; ++r) s += b2f(eb[r * HID + f]);
  s *= (1.f / PL);
  gf_s[f] = s;
  { size_t ei = (size_t)GF_EOFF + (size_t)g * HID + f;
    if (fl) ((float*)dout)[ei] = s; else ((bf16*)dout)[ei] = __float2bfloat16(s); }
  __syncthreads();
  float acc = P[CB1_OFF + f];
  for (int k = 0; k < HID; k += 4) {
    const float4 gv = *(const float4*)(&gf_s[k]);
    acc = fmaf(gv.x, P[W1T_OFF + (k + 0) * HID + f], acc);
    acc = fmaf(gv.y, P[W1T_OFF + (k + 1) * HID + f], acc);
    acc = fmaf(gv.z, P[W1T_OFF + (k + 2) * HID + f], acc);
    acc = fmaf(gv.w, P[W1T_OFF + (k + 3) * HID + f], acc);
  }
  float s1 = acc, s2 = acc * acc;
#pragma unroll
  for (int m = 32; m >= 1; m >>= 1) { s1 += __shfl_xor(s1, m); s2 += __shfl_xor(s2, m); }
  int wid = f >> 6, lane = f & 63;
  if (lane == 0) { ps[wid] = s1; ps2[wid] = s2; }
  __syncthreads();
  if (f == 0) {
    float S = ps[0] + ps[1] + ps[2] + ps[3];
    float S2 = ps2[0] + ps2[1] + ps2[2] + ps2[3];
    float mean = S * (1.f / HID);
    mr[0] = mean; mr[1] = rsqrtf(S2 * (1.f / HID) - mean * mean + 1e-5f);
  }
  __syncthreads();
  float z = (acc - mr[0]) * mr[1] * P[CLNS_OFF + f] + P[CLNB_OFF + f];
  z = z > 0.f ? z : 0.f;
  z_s[f] = z;
  __syncthreads();
  if (f < NCLS) {
    float a = P[CB2_OFF + f];
    for (int k = 0; k < HID; ++k) a = fmaf(z_s[k], P[CW2_OFF + f * HID + k], a);
    size_t ei = (size_t)g * NCLS + f;
    if (fl) ((float*)dout)[ei] = a; else ((bf16*)dout)[ei] = __float2bfloat16(a);
  }
}

// -------- emit node_emb --------
__global__ __launch_bounds__(256) void emit_emb(
    const bf16* __restrict__ A, void* __restrict__ dout, const int* __restrict__ flag) {
  int fl = *flag;
  size_t n = (size_t)NNODE * HID;
  for (size_t i = blockIdx.x * 256ull + threadIdx.x; i < n; i += 2048ull * 256ull) {
    bf16 v = A[i];
    size_t ei = (size_t)EMB_EOFF + i;
    if (fl) ((float*)dout)[ei] = b2f(v); else ((bf16*)dout)[ei] = v;
  }
}

extern "C" void kernel_launch(void* const* d_in, const int* in_sizes, int n_in,
                              void* d_out, int out_size, void* d_ws, size_t ws_size,
                              hipStream_t stream) {
  char* ws = (char*)d_ws;
  int*   flag = (int*)ws;
  float* P    = (float*)(ws + P_BYTE_OFF);
  bf16*  WB   = (bf16*)(ws + WB_BYTE_OFF);
  bf16*  A    = (bf16*)(ws + A_BYTE_OFF);
  bf16*  B    = (bf16*)((char*)d_out + B_BYTE_OFF);

  detect_kernel<<<1, 256, 0, stream>>>((const u16*)d_in[0], flag);
  convert_params<<<(CVT_TOTAL + 255) / 256, 256, 0, stream>>>(
      flag, d_in[0], d_in[3], d_in[4], d_in[5], d_in[8],
      d_in[9], d_in[10], d_in[11], d_in[12], d_in[13], d_in[14], d_in[15], d_in[16], P);
  convert_wb<<<1536, 256, 0, stream>>>(flag, d_in[6], d_in[7], WB);

  layer0_kernel<<<NG, 256, 0, stream>>>(P, B);
  sage_mfma<<<NG / BP, 256, 0, stream>>>(B, WB, WB + 65536,
      P + BLIN_OFF, P + LNS_OFF + HID, P + LNB_OFF + HID, A);
  sage_mfma<<<NG / BP, 256, 0, stream>>>(A, WB + 131072, WB + 131072 + 65536,
      P + BLIN_OFF + HID, P + LNS_OFF + 2 * HID, P + LNB_OFF + 2 * HID, B);
  sage_mfma<<<NG / BP, 256, 0, stream>>>(B, WB + 262144, WB + 262144 + 65536,
      P + BLIN_OFF + 2 * HID, P + LNS_OFF + 3 * HID, P + LNB_OFF + 3 * HID, A);
  head_kernel<<<NG, 256, 0, stream>>>(A, P, d_out, flag);
  emit_emb<<<2048, 256, 0, stream>>>(A, d_out, flag);
}

// Round 6
// 238.049 us; speedup vs baseline: 4.1440x; 1.3036x over previous
//
#include <hip/hip_runtime.h>
#include <hip/hip_bf16.h>

typedef __hip_bfloat16 bf16;
typedef unsigned short u16;
typedef unsigned int uint32;
typedef __attribute__((ext_vector_type(8))) short bf16x8;
typedef __attribute__((ext_vector_type(4))) float f32x4;

#define BATCH   128
#define LSIG    128
#define PL      16
#define ST      4
#define WIN     4
#define NPATCH  29
#define NG      (BATCH * NPATCH)   // 3712
#define NNODE   (NG * PL)          // 59392
#define HID     256
#define NCLS    8

// f32 param workspace layout (element offsets)
#define IQ_OFF    0
#define W0A_OFF   32768
#define W0R_OFF   33280
#define B0_OFF    33792
#define BLIN_OFF  34048
#define LNS_OFF   34816
#define LNB_OFF   35840
#define W1T_OFF   36864
#define CB1_OFF   102400
#define CLNS_OFF  102656
#define CLNB_OFF  102912
#define CW2_OFF   103168
#define CB2_OFF   105216
#define CVT_TOTAL 105224

#define P_BYTE_OFF   4096
#define WB_BYTE_OFF  425984           // bf16 sage weights: 3 layers x (Wa|Wr) x 65536
#define A_BYTE_OFF   1216512          // bf16 activation buffer (30.4 MB)
#define B_BYTE_OFF   1959936          // bf16 scratch window inside d_out
#define GF_EOFF      (NG * NCLS)
#define EMB_EOFF     (NG * NCLS + NG * HID)

__device__ __forceinline__ float b2f(bf16 x) { return __bfloat162float(x); }
__device__ __forceinline__ float lof(uint32 u) { return __uint_as_float(u << 16); }
__device__ __forceinline__ float hif(uint32 u) { return __uint_as_float(u & 0xFFFF0000u); }
__device__ __forceinline__ float ldmix(const void* p, int i, int fl) {
  return fl ? ((const float*)p)[i] : __bfloat162float(((const bf16*)p)[i]);
}

// -------- dtype detector --------
__global__ __launch_bounds__(256) void detect_kernel(const u16* __restrict__ iq, int* flag) {
  __shared__ int sbig, snz;
  int t = threadIdx.x;
  if (t == 0) { sbig = 0; snz = 0; }
  __syncthreads();
  int big = 0, nz = 0;
  for (int e = t; e < 16384; e += 256) {
    u16 u = iq[2 * e];
    int ex = (u >> 7) & 0xFF;
    if (ex >= 0xC0) big++;
    if (u != 0) nz++;
  }
  atomicAdd(&sbig, big); atomicAdd(&snz, nz);
  __syncthreads();
  if (t == 0) *flag = (sbig > 4 || snz < 100) ? 1 : 0;   // 1 = f32 inputs
}

// -------- params -> f32 P --------
__global__ __launch_bounds__(256) void convert_params(
    const int* __restrict__ flag,
    const void* iq, const void* w0a, const void* w0r, const void* b0,
    const void* blin, const void* lns, const void* lnb,
    const void* cw1, const void* cb1, const void* clns, const void* clnb,
    const void* cw2, const void* cb2,
    float* __restrict__ P) {
  int idx = blockIdx.x * 256 + threadIdx.x;
  if (idx >= CVT_TOTAL) return;
  int fl = *flag;
  float v;
  if (idx < W0A_OFF)        v = ldmix(iq,  idx, fl);
  else if (idx < W0R_OFF)   v = ldmix(w0a, idx - W0A_OFF, fl);
  else if (idx < B0_OFF)    v = ldmix(w0r, idx - W0R_OFF, fl);
  else if (idx < BLIN_OFF)  v = ldmix(b0,  idx - B0_OFF, fl);
  else if (idx < LNS_OFF)   v = ldmix(blin, idx - BLIN_OFF, fl);
  else if (idx < LNB_OFF)   v = ldmix(lns, idx - LNS_OFF, fl);
  else if (idx < W1T_OFF)   v = ldmix(lnb, idx - LNB_OFF, fl);
  else if (idx < CB1_OFF) { int t2 = idx - W1T_OFF;
    v = ldmix(cw1, (t2 & 255) * 256 + (t2 >> 8), fl); }
  else if (idx < CLNS_OFF)  v = ldmix(cb1, idx - CB1_OFF, fl);
  else if (idx < CLNB_OFF)  v = ldmix(clns, idx - CLNS_OFF, fl);
  else if (idx < CW2_OFF)   v = ldmix(clnb, idx - CLNB_OFF, fl);
  else if (idx < CB2_OFF)   v = ldmix(cw2, idx - CW2_OFF, fl);
  else                      v = ldmix(cb2, idx - CB2_OFF, fl);
  P[idx] = v;
}

// -------- sage weights -> bf16 WB ([f][k] layout kept) --------
__global__ __launch_bounds__(256) void convert_wb(
    const int* __restrict__ flag, const void* wag, const void* wro, bf16* __restrict__ WB) {
  int idx = blockIdx.x * 256 + threadIdx.x;   // < 393216
  int fl = *flag;
  int l = idx >> 17, m = (idx >> 16) & 1, r = idx & 65535;
  const void* src = m ? wro : wag;
  WB[idx] = __float2bfloat16(ldmix(src, l * 65536 + r, fl));
}

// -------- layer 0: patch extract + SAGE(2->256) + LN + ReLU --------
__global__ __launch_bounds__(256) void layer0_kernel(
    const float* __restrict__ P, bf16* __restrict__ hout) {
  int g = blockIdx.x, f = threadIdx.x;
  int b = g / NPATCH, p = g % NPATCH;
  __shared__ float x_s[PL][2];
  __shared__ float xp_s[2];
  __shared__ float agg_s[PL][2];
  __shared__ float o_s[PL][HID];
  __shared__ float mv_s[PL][2];
  if (f < 32) { int j = f & 15, c = f >> 4;
    x_s[j][c] = P[IQ_OFF + (b * 2 + c) * LSIG + p * ST + j]; }
  if (f < 2) xp_s[f] = (p > 0) ? P[IQ_OFF + (b * 2 + f) * LSIG + (p - 1) * ST + PL - 1] : 0.f;
  __syncthreads();
  if (f < 32) { int j = f & 15, c = f >> 4;
    float s = 0.f;
    int lo = j - WIN < 0 ? 0 : j - WIN, hi = j + WIN > 15 ? 15 : j + WIN;
    for (int i = lo; i <= hi; ++i) if (i != j) s += x_s[i][c];
    int deg = (j < WIN ? j : WIN) + ((15 - j) < WIN ? (15 - j) : WIN);
    if (j == 0 && p > 0) { s += xp_s[c]; deg += 1; }
    agg_s[j][c] = s / (float)deg;
  }
  __syncthreads();
  float wa0 = P[W0A_OFF + f * 2], wa1 = P[W0A_OFF + f * 2 + 1];
  float wr0 = P[W0R_OFF + f * 2], wr1 = P[W0R_OFF + f * 2 + 1];
  float bb = P[B0_OFF + f];
#pragma unroll
  for (int j = 0; j < PL; ++j)
    o_s[j][f] = agg_s[j][0] * wa0 + agg_s[j][1] * wa1 + x_s[j][0] * wr0 + x_s[j][1] * wr1 + bb;
  __syncthreads();
  { int j = f >> 4, q = f & 15;
    float s = 0.f, s2 = 0.f;
#pragma unroll
    for (int i = 0; i < 16; ++i) { float v = o_s[j][q + 16 * i]; s += v; s2 += v * v; }
#pragma unroll
    for (int m = 8; m >= 1; m >>= 1) { s += __shfl_xor(s, m); s2 += __shfl_xor(s2, m); }
    if (q == 0) { float mean = s * (1.f / HID);
      float var = s2 * (1.f / HID) - mean * mean;
      mv_s[j][0] = mean; mv_s[j][1] = rsqrtf(var + 1e-5f); }
  }
  __syncthreads();
  float gl = P[LNS_OFF + f], bl = P[LNB_OFF + f];
#pragma unroll
  for (int j = 0; j < PL; ++j) {
    float v = (o_s[j][f] - mv_s[j][0]) * mv_s[j][1] * gl + bl;
    v = v > 0.f ? v : 0.f;
    hout[(size_t)(g * PL + j) * HID + f] = __float2bfloat16(v);
  }
}

// -------- SAGE layer 256->256 via MFMA + LN + ReLU + residual --------
// BP=4: M=64 rows (4 patches), 4 waves x 64 cols. LDS = 64KB exactly:
// h32[64][128 dw] + a32[64][128 dw], row-XOR swizzle (16B slot ^= row&7).
#define MFMA_BF16 __builtin_amdgcn_mfma_f32_16x16x32_bf16
__global__ __launch_bounds__(256, 2) void sage_mfma(
    const bf16* __restrict__ hin,
    const bf16* __restrict__ Wa, const bf16* __restrict__ Wr,
    const float* __restrict__ bias,
    const float* __restrict__ lng, const float* __restrict__ lnb,
    bf16* __restrict__ hout) {
  int t = threadIdx.x;
  int w = t >> 6, l = t & 63, lr = l & 15, lg = l >> 4;
  int g0 = blockIdx.x * 4;
  size_t nbase = (size_t)g0 * PL;
  __shared__ uint32 h32[64 * 128];
  __shared__ uint32 a32[64 * 128];
  float* mvp = (float*)h32;                 // aliased after h32 is dead
  const uint32* hinw = (const uint32*)hin;

  // ---- B preload (nt 0,1; all ks) : 128 VGPRs, latency hides under stage+agg ----
  int colbase = w * 64;
  const bf16* waB = Wa + (colbase + lr) * HID + lg * 8;
  const bf16* wrB = Wr + (colbase + lr) * HID + lg * 8;
  bf16x8 wa0[2][8], wr0[2][8];
#pragma unroll
  for (int nt = 0; nt < 2; ++nt)
#pragma unroll
    for (int ks = 0; ks < 8; ++ks) {
      wa0[nt][ks] = *(const bf16x8*)(waB + nt * 16 * HID + ks * 32);
      wr0[nt][ks] = *(const bf16x8*)(wrB + nt * 16 * HID + ks * 32);
    }

  // ---- stage h: 64 rows x 32 slots(16B), swizzled ----
  const uint32* hg = hinw + nbase * 128;
#pragma unroll
  for (int it = 0; it < 8; ++it) {
    int u = it * 256 + t;
    int row = u >> 5, sl = u & 31;
    int sw = sl ^ (row & 7);
    *(uint4*)&h32[row * 128 + sw * 4] = *(const uint4*)(hg + u * 4);
  }
  __syncthreads();

  // ---- agg (windowed mean) : thread = (col-pair c2, patch-half) ----
  {
    int c2 = t & 127, Ph = t >> 7;
#pragma unroll
    for (int pi = 0; pi < 2; ++pi) {
      int pp = Ph + pi * 2;
      int pr = pp * 16;
      int hp = ((g0 + pp) % NPATCH) != 0;
      float vlo[16], vhi[16];
#pragma unroll
      for (int j = 0; j < 16; ++j) {
        uint32 u = h32[(pr + j) * 128 + (((c2 >> 2) ^ (j & 7)) << 2) + (c2 & 3)];
        vlo[j] = lof(u); vhi[j] = hif(u);
      }
      float blo = 0.f, bhi = 0.f;
      if (hp) {
        uint32 u;
        if (pp == 0) u = hinw[(nbase - 1) * 128 + c2];
        else { int br = pr - 1;
          u = a32[0]; // placeholder never used
          u = h32[br * 128 + (((c2 >> 2) ^ (br & 7)) << 2) + (c2 & 3)]; }
        blo = lof(u); bhi = hif(u);
      }
#pragma unroll
      for (int j = 0; j < 16; ++j) {
        const int a = (j - WIN < 0) ? 0 : j - WIN;
        const int b = (j + WIN > 15) ? 15 : j + WIN;
        float slo = 0.f, shi = 0.f;
#pragma unroll
        for (int i = 0; i < 16; ++i)
          if (i >= a && i <= b && i != j) { slo += vlo[i]; shi += vhi[i]; }
        float deg = (float)((j < WIN ? j : WIN) + (15 - j < WIN ? 15 - j : WIN));
        if (j == 0 && hp) { slo += blo; shi += bhi; deg += 1.f; }
        float inv = 1.f / deg;
        bf16 r0 = __float2bfloat16(slo * inv), r1 = __float2bfloat16(shi * inv);
        uint32 wv = ((uint32)(*(const u16*)&r1) << 16) | (uint32)(*(const u16*)&r0);
        a32[(pr + j) * 128 + (((c2 >> 2) ^ (j & 7)) << 2) + (c2 & 3)] = wv;
      }
    }
  }
  __syncthreads();

  // ---- MFMA GEMM: out = agg@Wa^T + h@Wr^T ----
  f32x4 acc[4][4];
#pragma unroll
  for (int m = 0; m < 4; ++m)
#pragma unroll
    for (int n = 0; n < 4; ++n) acc[m][n] = (f32x4){0.f, 0.f, 0.f, 0.f};
#pragma unroll
  for (int ks = 0; ks < 8; ++ks) {
    bf16x8 wa1[2], wr1[2];
#pragma unroll
    for (int nt = 0; nt < 2; ++nt) {
      wa1[nt] = *(const bf16x8*)(waB + (nt + 2) * 16 * HID + ks * 32);
      wr1[nt] = *(const bf16x8*)(wrB + (nt + 2) * 16 * HID + ks * 32);
    }
#pragma unroll
    for (int m = 0; m < 4; ++m) {
      int row = m * 16 + lr;
      int idx = row * 128 + ((((ks * 4 + lg) ^ (lr & 7))) << 2);
      bf16x8 af = *(const bf16x8*)&a32[idx];
      bf16x8 hf = *(const bf16x8*)&h32[idx];
      acc[m][0] = MFMA_BF16(af, wa0[0][ks], acc[m][0], 0, 0, 0);
      acc[m][0] = MFMA_BF16(hf, wr0[0][ks], acc[m][0], 0, 0, 0);
      acc[m][1] = MFMA_BF16(af, wa0[1][ks], acc[m][1], 0, 0, 0);
      acc[m][1] = MFMA_BF16(hf, wr0[1][ks], acc[m][1], 0, 0, 0);
      acc[m][2] = MFMA_BF16(af, wa1[0],     acc[m][2], 0, 0, 0);
      acc[m][2] = MFMA_BF16(hf, wr1[0],     acc[m][2], 0, 0, 0);
      acc[m][3] = MFMA_BF16(af, wa1[1],     acc[m][3], 0, 0, 0);
      acc[m][3] = MFMA_BF16(hf, wr1[1],     acc[m][3], 0, 0, 0);
    }
  }
  // bias (per output column)
#pragma unroll
  for (int nt = 0; nt < 4; ++nt) {
    float bv = bias[colbase + nt * 16 + lr];
#pragma unroll
    for (int m = 0; m < 4; ++m) {
      acc[m][nt][0] += bv; acc[m][nt][1] += bv;
      acc[m][nt][2] += bv; acc[m][nt][3] += bv;
    }
  }
  __syncthreads();                 // all A-frag reads done

  // ---- store o into a32 (D layout: col=lane&15, row=(lane>>4)*4+reg) ----
#pragma unroll
  for (int m = 0; m < 4; ++m)
#pragma unroll
    for (int nt = 0; nt < 4; ++nt) {
      int col = colbase + nt * 16 + lr;
#pragma unroll
      for (int r = 0; r < 4; ++r) {
        int row = m * 16 + lg * 4 + r;
        int i16 = row * 256 + (((col >> 3) ^ (row & 7)) << 3) + (col & 7);
        bf16 x = __float2bfloat16(acc[m][nt][r]);
        ((u16*)a32)[i16] = *(const u16*)&x;
      }
    }
  __syncthreads();

  // ---- LN stats: 4 threads per row; mean/rstd -> mvp (aliases dead h32) ----
  {
    int row = t >> 2, q = t & 3;
    float s = 0.f, s2 = 0.f;
#pragma unroll
    for (int i = 0; i < 32; ++i) {
      int d = q * 32 + i;
      uint32 u = a32[row * 128 + (((d >> 2) ^ (row & 7)) << 2) + (d & 3)];
      float a = lof(u), b = hif(u);
      s += a + b; s2 += a * a + b * b;
    }
    s += __shfl_xor(s, 1); s2 += __shfl_xor(s2, 1);
    s += __shfl_xor(s, 2); s2 += __shfl_xor(s2, 2);
    if (q == 0) { float mean = s * (1.f / HID);
      mvp[row * 2] = mean;
      mvp[row * 2 + 1] = rsqrtf(s2 * (1.f / HID) - mean * mean + 1e-5f); }
  }
  __syncthreads();

  // ---- LN + ReLU + residual (from global, L2-hot) + store ----
  {
    int c2 = t & 127, part = t >> 7;
    float gl0 = lng[c2 * 2], gl1 = lng[c2 * 2 + 1];
    float bl0 = lnb[c2 * 2], bl1 = lnb[c2 * 2 + 1];
    uint32* outw = (uint32*)hout + nbase * 128;
    const uint32* inw = hinw + nbase * 128;
#pragma unroll
    for (int i = 0; i < 32; ++i) {
      int row = part * 32 + i;
      uint32 u = a32[row * 128 + (((c2 >> 2) ^ (row & 7)) << 2) + (c2 & 3)];
      float mean = mvp[row * 2], rstd = mvp[row * 2 + 1];
      float a = (lof(u) - mean) * rstd * gl0 + bl0; a = a > 0.f ? a : 0.f;
      float b = (hif(u) - mean) * rstd * gl1 + bl1; b = b > 0.f ? b : 0.f;
      uint32 hu = inw[row * 128 + c2];
      a += lof(hu); b += hif(hu);
      bf16 r0 = __float2bfloat16(a), r1 = __float2bfloat16(b);
      uint32 wv = ((uint32)(*(const u16*)&r1) << 16) | (uint32)(*(const u16*)&r0);
      outw[row * 128 + c2] = wv;
    }
  }
}

// -------- head --------
__global__ __launch_bounds__(256) void head_kernel(
    const bf16* __restrict__ emb, const float* __restrict__ P,
    void* __restrict__ dout, const int* __restrict__ flag) {
  int g = blockIdx.x, f = threadIdx.x;
  int fl = *flag;
  __shared__ float gf_s[HID];
  __shared__ float z_s[HID];
  __shared__ float ps[4], ps2[4];
  __shared__ float mr[2];
  const bf16* eb = emb + (size_t)g * PL * HID;
  float s = 0.f;
#pragma unroll
  for (int r = 0; r < PL; ++r) s += b2f(eb[r * HID + f]);
  s *= (1.f / PL);
  gf_s[f] = s;
  { size_t ei = (size_t)GF_EOFF + (size_t)g * HID + f;
    if (fl) ((float*)dout)[ei] = s; else ((bf16*)dout)[ei] = __float2bfloat16(s); }
  __syncthreads();
  float acc = P[CB1_OFF + f];
  for (int k = 0; k < HID; k += 4) {
    const float4 gv = *(const float4*)(&gf_s[k]);
    acc = fmaf(gv.x, P[W1T_OFF + (k + 0) * HID + f], acc);
    acc = fmaf(gv.y, P[W1T_OFF + (k + 1) * HID + f], acc);
    acc = fmaf(gv.z, P[W1T_OFF + (k + 2) * HID + f], acc);
    acc = fmaf(gv.w, P[W1T_OFF + (k + 3) * HID + f], acc);
  }
  float s1 = acc, s2 = acc * acc;
#pragma unroll
  for (int m = 32; m >= 1; m >>= 1) { s1 += __shfl_xor(s1, m); s2 += __shfl_xor(s2, m); }
  int wid = f >> 6, lane = f & 63;
  if (lane == 0) { ps[wid] = s1; ps2[wid] = s2; }
  __syncthreads();
  if (f == 0) {
    float S = ps[0] + ps[1] + ps[2] + ps[3];
    float S2 = ps2[0] + ps2[1] + ps2[2] + ps2[3];
    float mean = S * (1.f / HID);
    mr[0] = mean; mr[1] = rsqrtf(S2 * (1.f / HID) - mean * mean + 1e-5f);
  }
  __syncthreads();
  float z = (acc - mr[0]) * mr[1] * P[CLNS_OFF + f] + P[CLNB_OFF + f];
  z = z > 0.f ? z : 0.f;
  z_s[f] = z;
  __syncthreads();
  if (f < NCLS) {
    float a = P[CB2_OFF + f];
    for (int k = 0; k < HID; ++k) a = fmaf(z_s[k], P[CW2_OFF + f * HID + k], a);
    size_t ei = (size_t)g * NCLS + f;
    if (fl) ((float*)dout)[ei] = a; else ((bf16*)dout)[ei] = __float2bfloat16(a);
  }
}

// -------- emit node_emb --------
__global__ __launch_bounds__(256) void emit_emb(
    const bf16* __restrict__ A, void* __restrict__ dout, const int* __restrict__ flag) {
  int fl = *flag;
  size_t n = (size_t)NNODE * HID;
  for (size_t i = blockIdx.x * 256ull + threadIdx.x; i < n; i += 2048ull * 256ull) {
    bf16 v = A[i];
    size_t ei = (size_t)EMB_EOFF + i;
    if (fl) ((float*)dout)[ei] = b2f(v); else ((bf16*)dout)[ei] = v;
  }
}

extern "C" void kernel_launch(void* const* d_in, const int* in_sizes, int n_in,
                              void* d_out, int out_size, void* d_ws, size_t ws_size,
                              hipStream_t stream) {
  char* ws = (char*)d_ws;
  int*   flag = (int*)ws;
  float* P    = (float*)(ws + P_BYTE_OFF);
  bf16*  WB   = (bf16*)(ws + WB_BYTE_OFF);
  bf16*  A    = (bf16*)(ws + A_BYTE_OFF);
  bf16*  B    = (bf16*)((char*)d_out + B_BYTE_OFF);

  detect_kernel<<<1, 256, 0, stream>>>((const u16*)d_in[0], flag);
  convert_params<<<(CVT_TOTAL + 255) / 256, 256, 0, stream>>>(
      flag, d_in[0], d_in[3], d_in[4], d_in[5], d_in[8],
      d_in[9], d_in[10], d_in[11], d_in[12], d_in[13], d_in[14], d_in[15], d_in[16], P);
  convert_wb<<<1536, 256, 0, stream>>>(flag, d_in[6], d_in[7], WB);

  layer0_kernel<<<NG, 256, 0, stream>>>(P, B);
  sage_mfma<<<NG / 4, 256, 0, stream>>>(B, WB, WB + 65536,
      P + BLIN_OFF, P + LNS_OFF + HID, P + LNB_OFF + HID, A);
  sage_mfma<<<NG / 4, 256, 0, stream>>>(A, WB + 131072, WB + 131072 + 65536,
      P + BLIN_OFF + HID, P + LNS_OFF + 2 * HID, P + LNB_OFF + 2 * HID, B);
  sage_mfma<<<NG / 4, 256, 0, stream>>>(B, WB + 262144, WB + 262144 + 65536,
      P + BLIN_OFF + 2 * HID, P + LNS_OFF + 3 * HID, P + LNB_OFF + 3 * HID, A);
  head_kernel<<<NG, 256, 0, stream>>>(A, P, d_out, flag);
  emit_emb<<<2048, 256, 0, stream>>>(A, d_out, flag);
}